// Round 7
// baseline (2061.197 us; speedup 1.0000x reference)
//
#include <hip/hip_runtime.h>
#include <math.h>

#define B_   16
#define N_   2048
#define K_   20
#define C_   64
#define OUT_ 64
#define NEG_SLOPE 0.2f

// ---------------------------------------------------------------------------
// Kernel 1: KNN — one wave per point (bit-identical math since R4).
// ---------------------------------------------------------------------------
__global__ __launch_bounds__(256, 2)
void knn_kernel(const float* __restrict__ pos, int* __restrict__ idx_out) {
    const int t = threadIdx.x;
    const int wv = t >> 6, l = t & 63;
    const int gid = blockIdx.x * 4 + wv;
    const int b = gid / N_, n = gid % N_;
    const float* pb = pos + (size_t)b * 3 * N_;

    const double qx = (double)pb[n];
    const double qy = (double)pb[N_ + n];
    const double qz = (double)pb[2 * N_ + n];
    const double xxn = qx * qx + qy * qy + qz * qz;

    double d[32];
    const int m0 = l * 32;
#pragma unroll
    for (int j4 = 0; j4 < 8; ++j4) {
        float4 px = *(const float4*)(pb + m0 + 4 * j4);
        float4 py = *(const float4*)(pb + N_ + m0 + 4 * j4);
        float4 pz = *(const float4*)(pb + 2 * N_ + m0 + 4 * j4);
#define DCOMP(JJ, PX, PY, PZ)                                            \
        {   double ddx = (double)(PX), ddy = (double)(PY), ddz = (double)(PZ); \
            double inner = qx * ddx + qy * ddy + qz * ddz;               \
            double xxm   = ddx * ddx + ddy * ddy + ddz * ddz;            \
            d[4 * j4 + JJ] = 2.0 * inner - xxn - xxm; }
        DCOMP(0, px.x, py.x, pz.x)
        DCOMP(1, px.y, py.y, pz.y)
        DCOMP(2, px.z, py.z, pz.z)
        DCOMP(3, px.w, py.w, pz.w)
#undef DCOMP
    }

    unsigned sel = 0u;
    for (int r = 0; r < K_ + 1; ++r) {
        double bk = -INFINITY;
        int bi = 0x7FFFFFFF;
#pragma unroll
        for (int j = 0; j < 32; ++j) {
            bool live = ((sel >> j) & 1u) == 0u;
            if (live && d[j] > bk) { bk = d[j]; bi = m0 + j; }
        }
#pragma unroll
        for (int off = 1; off < 64; off <<= 1) {
            double ok = __shfl_xor(bk, off, 64);
            int    oi = __shfl_xor(bi, off, 64);
            if (ok > bk || (ok == bk && oi < bi)) { bk = ok; bi = oi; }
        }
        if ((bi >> 5) == l) sel |= 1u << (bi & 31);
        if (l == 0 && r > 0) idx_out[(size_t)gid * K_ + (r - 1)] = bi;
    }
}

// ---------------------------------------------------------------------------
// Kernel 2: bxT[b][n][o] = sum_c basis_W[o,c] * x[b,c,n]   (transposed out)
// ---------------------------------------------------------------------------
__global__ __launch_bounds__(256)
void bx_kernel_t(const float* __restrict__ x, const float* __restrict__ W,
                 float* __restrict__ bxT) {
    __shared__ float wS[64 * 65];
    __shared__ float xS[64 * 33];
    const int t = threadIdx.x;
    const int b = blockIdx.y;
    const int n0 = blockIdx.x * 32;

    for (int i = t; i < 64 * 64; i += 256) {
        int r = i >> 6, c = i & 63;
        wS[r * 65 + c] = W[i];
    }
    for (int i = t; i < 64 * 32; i += 256) {
        int c = i >> 5, j = i & 31;
        xS[c * 33 + j] = x[((size_t)b * C_ + c) * N_ + n0 + j];
    }
    __syncthreads();

    const int o = t & 63, j0 = t >> 6;
#pragma unroll 1
    for (int j = j0; j < 32; j += 4) {
        float acc = 0.f;
#pragma unroll
        for (int c = 0; c < 64; ++c)
            acc = fmaf(wS[o * 65 + c], xS[c * 33 + j], acc);
        bxT[((size_t)b * N_ + n0 + j) * 64 + o] = acc;
    }
}

// ---------------------------------------------------------------------------
// Kernel 3: fused pipeline — one wave per point, zero barriers.
// R7 change: k-stages tiled into chunks of KC=5 accumulators (outer chunk
// loops pinned no-unroll) so live-register demand fits without scratch
// spills. R6 evidence: spilling persisted at VGPR=128 (acc2[20] + hoisted
// loads); spill traffic was ~1.2 GB fetch + 0.69 GB write.
// Accumulation order per k unchanged -> bit-identical output.
// ---------------------------------------------------------------------------
#define WPB 4
#define NPW 4
#define NBLK (WPB * NPW)   // 16 n per block
#define SLICE 2048         // floats per wave slice (8 KB)

__global__ __launch_bounds__(256, 2)
void fused_kernel(const float* __restrict__ x, const float* __restrict__ glf,
                  const float* __restrict__ appf,
                  const float* __restrict__ dk_W1, const float* __restrict__ dk_b1,
                  const float* __restrict__ dk_g1, const float* __restrict__ dk_be1,
                  const float* __restrict__ dk_W2, const float* __restrict__ dk_b2,
                  const float* __restrict__ act_g, const float* __restrict__ act_b,
                  const float* __restrict__ ff_W1, const float* __restrict__ ff_g1,
                  const float* __restrict__ ff_be1, const float* __restrict__ ff_W2,
                  const float* __restrict__ edge_W, const float* __restrict__ edge_g,
                  const float* __restrict__ edge_be,
                  const float* __restrict__ bxT, const int* __restrict__ idx_ws,
                  float* __restrict__ out) {
    __shared__ float lds[WPB * SLICE];
    const int t = threadIdx.x, wv = t >> 6, l = t & 63;
    float* Wb   = lds + wv * SLICE;
    float* RIF  = Wb;            // [20][64]
    float* SCR  = Wb + 1280;     // appf [20][8] @0 ; h [20][16] @160 ; t [20][32] @0
    float* XCOL = Wb + 1920;     // 64
    int*   IDX  = (int*)(Wb + 1984); // 20

    // XCD-aware swizzle: 2048 blocks = 8 XCD x 256; 2 b per XCD, 128 blocks/b.
    const int raw  = blockIdx.x;
    const int xcd  = raw & 7;
    const int slot = raw >> 3;                 // 0..255
    const int b    = xcd * 2 + (slot >> 7);    // 2 b per xcd
    const int nblk = (slot & 127) * NBLK;
    const int nw0  = nblk + wv * NPW;

    // ---- hoisted per-lane scalars (n-invariant) ----
    const int o16 = l >> 2, o32 = l >> 1;
    const int kq5 = (l & 3) * 5, kh10 = (l & 1) * 10;
    const float bdk1h = dk_b1[o16], gdk1h = dk_g1[o16], bedk1h = dk_be1[o16];
    const float bdk2h = dk_b2[o32];
    const float gff1h = ff_g1[o32], beff1h = ff_be1[o32];
    const float gacth = act_g[l],  bacth = act_b[l];
    const float gedgh = edge_g[l], beedgh = edge_be[l];
    const float* wF1  = ff_W1 + o32 * 64;
    const float* wF2  = ff_W2 + l * 32;
    const float* wEd  = edge_W + l * 128;
    const float* xrow  = x + ((size_t)b * C_ + l) * N_;
    const float* bxb   = bxT + (size_t)b * N_ * 64;

#pragma unroll 1
    for (int i = 0; i < NPW; ++i) {
        const int n = nw0 + i;

        // ---- per-n loads ----
        const float xc = xrow[n];
        XCOL[l] = xc;
        if (l < K_) IDX[l] = idx_ws[((size_t)b * N_ + n) * K_ + l];
        if (l >= 32) {                 // appf: 160 contiguous floats
            const int l2 = l - 32;
            const float4* src = (const float4*)(appf + ((size_t)b * N_ + n) * (K_ * 8));
            *(float4*)(SCR + 4 * l2) = src[l2];
            if (l2 < 8) *(float4*)(SCR + 128 + 4 * l2) = src[32 + l2];
        } else {                       // glf row c2=l -> RIF[k][32+l]
            const float* g = glf + (((size_t)b * 32 + l) * N_ + n) * K_;
#pragma unroll
            for (int kc = 0; kc < 5; ++kc) {
                float4 v = *(const float4*)(g + 4 * kc);
                RIF[(4 * kc + 0) * 64 + 32 + l] = v.x;
                RIF[(4 * kc + 1) * 64 + 32 + l] = v.y;
                RIF[(4 * kc + 2) * 64 + 32 + l] = v.z;
                RIF[(4 * kc + 3) * 64 + 32 + l] = v.w;
            }
        }

        // ---- base_l = edge_W[l, 64:128] . x ----
        float base = 0.f;
#pragma unroll
        for (int c = 0; c < 16; ++c) {
            float4 w4 = *(const float4*)(wEd + 64 + 4 * c);
            float4 x4 = *(const float4*)(XCOL + 4 * c);
            base = fmaf(w4.x, x4.x, base); base = fmaf(w4.y, x4.y, base);
            base = fmaf(w4.z, x4.z, base); base = fmaf(w4.w, x4.w, base);
        }

        // ---- h = relu(bn(dk_W1 @ appf + b1)) : lane -> o=l>>2, k=kq5+q ----
        {
            const float4 wd1a = *(const float4*)(dk_W1 + o16 * 8);
            const float4 wd1b = *(const float4*)(dk_W1 + o16 * 8 + 4);
#pragma unroll
            for (int q = 0; q < 5; ++q) {
                const int k = kq5 + q;
                float4 a0 = *(const float4*)(SCR + k * 8);
                float4 a1 = *(const float4*)(SCR + k * 8 + 4);
                float acc = bdk1h;
                acc = fmaf(wd1a.x, a0.x, acc); acc = fmaf(wd1a.y, a0.y, acc);
                acc = fmaf(wd1a.z, a0.z, acc); acc = fmaf(wd1a.w, a0.w, acc);
                acc = fmaf(wd1b.x, a1.x, acc); acc = fmaf(wd1b.y, a1.y, acc);
                acc = fmaf(wd1b.z, a1.z, acc); acc = fmaf(wd1b.w, a1.w, acc);
                float v = acc * gdk1h + bedk1h;
                SCR[160 + k * 16 + o16] = fmaxf(v, 0.f);
            }
        }

        // ---- rif[0:32] = dk_W2 @ h + b2 : lane -> o=l>>1, k=kh10+q ----
        {
            const float4 wd20 = *(const float4*)(dk_W2 + o32 * 16);
            const float4 wd21 = *(const float4*)(dk_W2 + o32 * 16 + 4);
            const float4 wd22 = *(const float4*)(dk_W2 + o32 * 16 + 8);
            const float4 wd23 = *(const float4*)(dk_W2 + o32 * 16 + 12);
#pragma unroll 2
            for (int q = 0; q < 10; ++q) {
                const int k = kh10 + q;
                const float* hr = SCR + 160 + k * 16;
                float4 h0 = *(const float4*)(hr);
                float4 h1 = *(const float4*)(hr + 4);
                float4 h2 = *(const float4*)(hr + 8);
                float4 h3 = *(const float4*)(hr + 12);
                float acc = bdk2h;
                acc = fmaf(wd20.x, h0.x, acc); acc = fmaf(wd20.y, h0.y, acc);
                acc = fmaf(wd20.z, h0.z, acc); acc = fmaf(wd20.w, h0.w, acc);
                acc = fmaf(wd21.x, h1.x, acc); acc = fmaf(wd21.y, h1.y, acc);
                acc = fmaf(wd21.z, h1.z, acc); acc = fmaf(wd21.w, h1.w, acc);
                acc = fmaf(wd22.x, h2.x, acc); acc = fmaf(wd22.y, h2.y, acc);
                acc = fmaf(wd22.z, h2.z, acc); acc = fmaf(wd22.w, h2.w, acc);
                acc = fmaf(wd23.x, h3.x, acc); acc = fmaf(wd23.y, h3.y, acc);
                acc = fmaf(wd23.z, h3.z, acc); acc = fmaf(wd23.w, h3.w, acc);
                RIF[k * 64 + o32] = acc;
            }
        }

        // ---- t = leaky(bn(ff_W1 @ rif)) : k-chunks of 5 ----
#pragma unroll 1
        for (int qc = 0; qc < 10; qc += 5) {
            float acc5[5];
#pragma unroll
            for (int q = 0; q < 5; ++q) acc5[q] = 0.f;
#pragma unroll
            for (int c = 0; c < 16; ++c) {
                float4 w4 = *(const float4*)(wF1 + 4 * c);
#pragma unroll
                for (int q = 0; q < 5; ++q) {
                    float4 r4 = *(const float4*)(RIF + (kh10 + qc + q) * 64 + 4 * c);
                    acc5[q] = fmaf(w4.x, r4.x, acc5[q]);
                    acc5[q] = fmaf(w4.y, r4.y, acc5[q]);
                    acc5[q] = fmaf(w4.z, r4.z, acc5[q]);
                    acc5[q] = fmaf(w4.w, r4.w, acc5[q]);
                }
            }
#pragma unroll
            for (int q = 0; q < 5; ++q) {
                float v = acc5[q] * gff1h + beff1h;
                v = (v >= 0.f) ? v : NEG_SLOPE * v;
                SCR[(kh10 + qc + q) * 32 + o32] = v;   // t overwrites appf/h (dead)
            }
        }

        // ---- att = sigmoid(ff_W2 @ t); feat = relu(bn(rif*att*gth)) - x ----
#pragma unroll 1
        for (int kc = 0; kc < 20; kc += 5) {
            float acc5[5];
#pragma unroll
            for (int q = 0; q < 5; ++q) acc5[q] = 0.f;
#pragma unroll
            for (int c = 0; c < 8; ++c) {
                float4 w4 = *(const float4*)(wF2 + 4 * c);
#pragma unroll
                for (int q = 0; q < 5; ++q) {
                    float4 t4 = *(const float4*)(SCR + (kc + q) * 32 + 4 * c);
                    acc5[q] = fmaf(w4.x, t4.x, acc5[q]);
                    acc5[q] = fmaf(w4.y, t4.y, acc5[q]);
                    acc5[q] = fmaf(w4.z, t4.z, acc5[q]);
                    acc5[q] = fmaf(w4.w, t4.w, acc5[q]);
                }
            }
#pragma unroll
            for (int q = 0; q < 5; ++q) {
                const int k = kc + q;
                float a = 1.f / (1.f + expf(-acc5[q]));
                int kidx = IDX[k];
                float gth = bxb[(size_t)kidx * 64 + l];   // coalesced 256 B row
                float v = RIF[k * 64 + l] * a * gth;
                v = v * gacth + bacth;
                v = fmaxf(v, 0.f) - xc;
                RIF[k * 64 + l] = v;
            }
        }

        // ---- edge conv + bn + leaky + max over k : k-chunks of 5 ----
        float mx = -INFINITY;
#pragma unroll 1
        for (int kc = 0; kc < 20; kc += 5) {
            float acc5[5];
#pragma unroll
            for (int q = 0; q < 5; ++q) acc5[q] = base;
#pragma unroll
            for (int c = 0; c < 16; ++c) {
                float4 w4 = *(const float4*)(wEd + 4 * c);
#pragma unroll
                for (int q = 0; q < 5; ++q) {
                    float4 r4 = *(const float4*)(RIF + (kc + q) * 64 + 4 * c);
                    acc5[q] = fmaf(w4.x, r4.x, acc5[q]);
                    acc5[q] = fmaf(w4.y, r4.y, acc5[q]);
                    acc5[q] = fmaf(w4.z, r4.z, acc5[q]);
                    acc5[q] = fmaf(w4.w, r4.w, acc5[q]);
                }
            }
#pragma unroll
            for (int q = 0; q < 5; ++q) {
                float v = acc5[q] * gedgh + beedgh;
                v = (v >= 0.f) ? v : NEG_SLOPE * v;
                mx = fmaxf(mx, v);
            }
        }
        out[((size_t)b * OUT_ + l) * N_ + n] = mx;
    }
}

// ---------------------------------------------------------------------------
extern "C" void kernel_launch(void* const* d_in, const int* in_sizes, int n_in,
                              void* d_out, int out_size, void* d_ws, size_t ws_size,
                              hipStream_t stream) {
    (void)in_sizes; (void)n_in; (void)out_size; (void)ws_size;
    const float* pos     = (const float*)d_in[0];
    const float* x       = (const float*)d_in[1];
    const float* glf     = (const float*)d_in[2];
    const float* appf    = (const float*)d_in[3];
    const float* basis_W = (const float*)d_in[4];
    const float* dk_W1   = (const float*)d_in[5];
    const float* dk_b1   = (const float*)d_in[6];
    const float* dk_g1   = (const float*)d_in[7];
    const float* dk_be1  = (const float*)d_in[8];
    const float* dk_W2   = (const float*)d_in[9];
    const float* dk_b2   = (const float*)d_in[10];
    const float* act_g   = (const float*)d_in[11];
    const float* act_b   = (const float*)d_in[12];
    const float* ff_W1   = (const float*)d_in[13];
    const float* ff_g1   = (const float*)d_in[14];
    const float* ff_be1  = (const float*)d_in[15];
    const float* ff_W2   = (const float*)d_in[16];
    const float* edge_W  = (const float*)d_in[17];
    const float* edge_g  = (const float*)d_in[18];
    const float* edge_be = (const float*)d_in[19];
    float* out = (float*)d_out;

    int*   idx_ws = (int*)d_ws;
    float* bxT    = (float*)((char*)d_ws + (size_t)B_ * N_ * K_ * sizeof(int));

    hipLaunchKernelGGL(knn_kernel, dim3(B_ * N_ / 4), dim3(256), 0, stream,
                       pos, idx_ws);
    hipLaunchKernelGGL(bx_kernel_t, dim3(N_ / 32, B_), dim3(256), 0, stream,
                       x, basis_W, bxT);
    hipLaunchKernelGGL(fused_kernel, dim3(B_ * (N_ / NBLK)), dim3(256), 0, stream,
                       x, glf, appf, dk_W1, dk_b1, dk_g1, dk_be1, dk_W2, dk_b2,
                       act_g, act_b, ff_W1, ff_g1, ff_be1, ff_W2,
                       edge_W, edge_g, edge_be, bxT, idx_ws, out);
}

// Round 8
// 1619.316 us; speedup vs baseline: 1.2729x; 1.2729x over previous
//
#include <hip/hip_runtime.h>
#include <math.h>

#define B_   16
#define N_   2048
#define K_   20
#define C_   64
#define OUT_ 64
#define NEG_SLOPE 0.2f

// ---------------------------------------------------------------------------
// Kernel 1: KNN — one wave per point (bit-identical math since R4).
// Plain __launch_bounds__(256): no min-waves hint — the (256,2)/(256,4)
// hints made the allocator target 2x the declared occupancy and spill.
// ---------------------------------------------------------------------------
__global__ __launch_bounds__(256)
void knn_kernel(const float* __restrict__ pos, int* __restrict__ idx_out) {
    const int t = threadIdx.x;
    const int wv = t >> 6, l = t & 63;
    const int gid = blockIdx.x * 4 + wv;
    const int b = gid / N_, n = gid % N_;
    const float* pb = pos + (size_t)b * 3 * N_;

    const double qx = (double)pb[n];
    const double qy = (double)pb[N_ + n];
    const double qz = (double)pb[2 * N_ + n];
    const double xxn = qx * qx + qy * qy + qz * qz;

    double d[32];
    const int m0 = l * 32;
#pragma unroll
    for (int j4 = 0; j4 < 8; ++j4) {
        float4 px = *(const float4*)(pb + m0 + 4 * j4);
        float4 py = *(const float4*)(pb + N_ + m0 + 4 * j4);
        float4 pz = *(const float4*)(pb + 2 * N_ + m0 + 4 * j4);
#define DCOMP(JJ, PX, PY, PZ)                                            \
        {   double ddx = (double)(PX), ddy = (double)(PY), ddz = (double)(PZ); \
            double inner = qx * ddx + qy * ddy + qz * ddz;               \
            double xxm   = ddx * ddx + ddy * ddy + ddz * ddz;            \
            d[4 * j4 + JJ] = 2.0 * inner - xxn - xxm; }
        DCOMP(0, px.x, py.x, pz.x)
        DCOMP(1, px.y, py.y, pz.y)
        DCOMP(2, px.z, py.z, pz.z)
        DCOMP(3, px.w, py.w, pz.w)
#undef DCOMP
    }

    unsigned sel = 0u;
    for (int r = 0; r < K_ + 1; ++r) {
        double bk = -INFINITY;
        int bi = 0x7FFFFFFF;
#pragma unroll
        for (int j = 0; j < 32; ++j) {
            bool live = ((sel >> j) & 1u) == 0u;
            if (live && d[j] > bk) { bk = d[j]; bi = m0 + j; }
        }
#pragma unroll
        for (int off = 1; off < 64; off <<= 1) {
            double ok = __shfl_xor(bk, off, 64);
            int    oi = __shfl_xor(bi, off, 64);
            if (ok > bk || (ok == bk && oi < bi)) { bk = ok; bi = oi; }
        }
        if ((bi >> 5) == l) sel |= 1u << (bi & 31);
        if (l == 0 && r > 0) idx_out[(size_t)gid * K_ + (r - 1)] = bi;
    }
}

// ---------------------------------------------------------------------------
// Kernel 2: bxT[b][n][o] = sum_c basis_W[o,c] * x[b,c,n]   (transposed out)
// ---------------------------------------------------------------------------
__global__ __launch_bounds__(256)
void bx_kernel_t(const float* __restrict__ x, const float* __restrict__ W,
                 float* __restrict__ bxT) {
    __shared__ float wS[64 * 65];
    __shared__ float xS[64 * 33];
    const int t = threadIdx.x;
    const int b = blockIdx.y;
    const int n0 = blockIdx.x * 32;

    for (int i = t; i < 64 * 64; i += 256) {
        int r = i >> 6, c = i & 63;
        wS[r * 65 + c] = W[i];
    }
    for (int i = t; i < 64 * 32; i += 256) {
        int c = i >> 5, j = i & 31;
        xS[c * 33 + j] = x[((size_t)b * C_ + c) * N_ + n0 + j];
    }
    __syncthreads();

    const int o = t & 63, j0 = t >> 6;
#pragma unroll 1
    for (int j = j0; j < 32; j += 4) {
        float acc = 0.f;
#pragma unroll
        for (int c = 0; c < 64; ++c)
            acc = fmaf(wS[o * 65 + c], xS[c * 33 + j], acc);
        bxT[((size_t)b * N_ + n0 + j) * 64 + o] = acc;
    }
}

// ---------------------------------------------------------------------------
// Kernel 3: fused pipeline — one wave per point, zero barriers.
// R8: body identical to R6 (full-unroll k loops, bit-identical output).
// Only change: __launch_bounds__(256) with NO min-waves arg. Evidence:
// R3's plain (256) -> 144 VGPR, zero spill; (256,4)->64 VGPR + spill;
// (256,2)->128 VGPR + spill. The min-waves hint makes the allocator
// target 2x the declared occupancy and spill ~GBs to scratch.
// ---------------------------------------------------------------------------
#define WPB 4
#define NPW 4
#define NBLK (WPB * NPW)   // 16 n per block
#define SLICE 2048         // floats per wave slice (8 KB)

__global__ __launch_bounds__(256)
void fused_kernel(const float* __restrict__ x, const float* __restrict__ glf,
                  const float* __restrict__ appf,
                  const float* __restrict__ dk_W1, const float* __restrict__ dk_b1,
                  const float* __restrict__ dk_g1, const float* __restrict__ dk_be1,
                  const float* __restrict__ dk_W2, const float* __restrict__ dk_b2,
                  const float* __restrict__ act_g, const float* __restrict__ act_b,
                  const float* __restrict__ ff_W1, const float* __restrict__ ff_g1,
                  const float* __restrict__ ff_be1, const float* __restrict__ ff_W2,
                  const float* __restrict__ edge_W, const float* __restrict__ edge_g,
                  const float* __restrict__ edge_be,
                  const float* __restrict__ bxT, const int* __restrict__ idx_ws,
                  float* __restrict__ out) {
    __shared__ float lds[WPB * SLICE];
    const int t = threadIdx.x, wv = t >> 6, l = t & 63;
    float* Wb   = lds + wv * SLICE;
    float* RIF  = Wb;            // [20][64]
    float* SCR  = Wb + 1280;     // appf [20][8] @0 ; h [20][16] @160 ; t [20][32] @0
    float* XCOL = Wb + 1920;     // 64
    int*   IDX  = (int*)(Wb + 1984); // 20

    // XCD-aware swizzle: 2048 blocks = 8 XCD x 256; 2 b per XCD, 128 blocks/b.
    const int raw  = blockIdx.x;
    const int xcd  = raw & 7;
    const int slot = raw >> 3;                 // 0..255
    const int b    = xcd * 2 + (slot >> 7);    // 2 b per xcd
    const int nblk = (slot & 127) * NBLK;
    const int nw0  = nblk + wv * NPW;

    // ---- hoisted per-lane constants (n-invariant) ----
    const int o16 = l >> 2, o32 = l >> 1;
    const int kq5 = (l & 3) * 5, kh10 = (l & 1) * 10;
    const float bdk1h = dk_b1[o16], gdk1h = dk_g1[o16], bedk1h = dk_be1[o16];
    const float bdk2h = dk_b2[o32];
    const float gff1h = ff_g1[o32], beff1h = ff_be1[o32];
    const float gacth = act_g[l],  bacth = act_b[l];
    const float gedgh = edge_g[l], beedgh = edge_be[l];
    const float4 wd1a = *(const float4*)(dk_W1 + o16 * 8);
    const float4 wd1b = *(const float4*)(dk_W1 + o16 * 8 + 4);
    const float4 wd20 = *(const float4*)(dk_W2 + o32 * 16);
    const float4 wd21 = *(const float4*)(dk_W2 + o32 * 16 + 4);
    const float4 wd22 = *(const float4*)(dk_W2 + o32 * 16 + 8);
    const float4 wd23 = *(const float4*)(dk_W2 + o32 * 16 + 12);
    const float* wF1  = ff_W1 + o32 * 64;
    const float* wF2  = ff_W2 + l * 32;
    const float* wEd  = edge_W + l * 128;
    const float* xrow  = x + ((size_t)b * C_ + l) * N_;
    const float* bxb   = bxT + (size_t)b * N_ * 64;

#pragma unroll 1
    for (int i = 0; i < NPW; ++i) {
        const int n = nw0 + i;

        // ---- per-n loads ----
        const float xc = xrow[n];
        XCOL[l] = xc;
        if (l < K_) IDX[l] = idx_ws[((size_t)b * N_ + n) * K_ + l];
        if (l >= 32) {                 // appf: 160 contiguous floats
            const int l2 = l - 32;
            const float4* src = (const float4*)(appf + ((size_t)b * N_ + n) * (K_ * 8));
            *(float4*)(SCR + 4 * l2) = src[l2];
            if (l2 < 8) *(float4*)(SCR + 128 + 4 * l2) = src[32 + l2];
        } else {                       // glf row c2=l -> RIF[k][32+l]
            const float* g = glf + (((size_t)b * 32 + l) * N_ + n) * K_;
#pragma unroll
            for (int kc = 0; kc < 5; ++kc) {
                float4 v = *(const float4*)(g + 4 * kc);
                RIF[(4 * kc + 0) * 64 + 32 + l] = v.x;
                RIF[(4 * kc + 1) * 64 + 32 + l] = v.y;
                RIF[(4 * kc + 2) * 64 + 32 + l] = v.z;
                RIF[(4 * kc + 3) * 64 + 32 + l] = v.w;
            }
        }

        // ---- base_l = edge_W[l, 64:128] . x ----
        float base = 0.f;
#pragma unroll
        for (int c = 0; c < 16; ++c) {
            float4 w4 = *(const float4*)(wEd + 64 + 4 * c);
            float4 x4 = *(const float4*)(XCOL + 4 * c);
            base = fmaf(w4.x, x4.x, base); base = fmaf(w4.y, x4.y, base);
            base = fmaf(w4.z, x4.z, base); base = fmaf(w4.w, x4.w, base);
        }

        // ---- h = relu(bn(dk_W1 @ appf + b1)) : lane -> o=l>>2, k=kq5+q ----
#pragma unroll
        for (int q = 0; q < 5; ++q) {
            const int k = kq5 + q;
            float4 a0 = *(const float4*)(SCR + k * 8);
            float4 a1 = *(const float4*)(SCR + k * 8 + 4);
            float acc = bdk1h;
            acc = fmaf(wd1a.x, a0.x, acc); acc = fmaf(wd1a.y, a0.y, acc);
            acc = fmaf(wd1a.z, a0.z, acc); acc = fmaf(wd1a.w, a0.w, acc);
            acc = fmaf(wd1b.x, a1.x, acc); acc = fmaf(wd1b.y, a1.y, acc);
            acc = fmaf(wd1b.z, a1.z, acc); acc = fmaf(wd1b.w, a1.w, acc);
            float v = acc * gdk1h + bedk1h;
            SCR[160 + k * 16 + o16] = fmaxf(v, 0.f);
        }

        // ---- rif[0:32] = dk_W2 @ h + b2 : lane -> o=l>>1, k=kh10+q ----
#pragma unroll
        for (int q = 0; q < 10; ++q) {
            const int k = kh10 + q;
            const float* hr = SCR + 160 + k * 16;
            float4 h0 = *(const float4*)(hr);
            float4 h1 = *(const float4*)(hr + 4);
            float4 h2 = *(const float4*)(hr + 8);
            float4 h3 = *(const float4*)(hr + 12);
            float acc = bdk2h;
            acc = fmaf(wd20.x, h0.x, acc); acc = fmaf(wd20.y, h0.y, acc);
            acc = fmaf(wd20.z, h0.z, acc); acc = fmaf(wd20.w, h0.w, acc);
            acc = fmaf(wd21.x, h1.x, acc); acc = fmaf(wd21.y, h1.y, acc);
            acc = fmaf(wd21.z, h1.z, acc); acc = fmaf(wd21.w, h1.w, acc);
            acc = fmaf(wd22.x, h2.x, acc); acc = fmaf(wd22.y, h2.y, acc);
            acc = fmaf(wd22.z, h2.z, acc); acc = fmaf(wd22.w, h2.w, acc);
            acc = fmaf(wd23.x, h3.x, acc); acc = fmaf(wd23.y, h3.y, acc);
            acc = fmaf(wd23.z, h3.z, acc); acc = fmaf(wd23.w, h3.w, acc);
            RIF[k * 64 + o32] = acc;
        }

        // ---- t = leaky(bn(ff_W1 @ rif)) : lane -> o=l>>1, k=kh10+q ----
        {
            float acc[10];
#pragma unroll
            for (int q = 0; q < 10; ++q) acc[q] = 0.f;
#pragma unroll
            for (int c = 0; c < 16; ++c) {
                float4 w4 = *(const float4*)(wF1 + 4 * c);
#pragma unroll
                for (int q = 0; q < 10; ++q) {
                    float4 r4 = *(const float4*)(RIF + (kh10 + q) * 64 + 4 * c);
                    acc[q] = fmaf(w4.x, r4.x, acc[q]);
                    acc[q] = fmaf(w4.y, r4.y, acc[q]);
                    acc[q] = fmaf(w4.z, r4.z, acc[q]);
                    acc[q] = fmaf(w4.w, r4.w, acc[q]);
                }
            }
#pragma unroll
            for (int q = 0; q < 10; ++q) {
                float v = acc[q] * gff1h + beff1h;
                v = (v >= 0.f) ? v : NEG_SLOPE * v;
                SCR[(kh10 + q) * 32 + o32] = v;   // t overwrites appf/h (dead)
            }
        }

        // ---- att = sigmoid(ff_W2 @ t); feat = relu(bn(rif*att*gather)) - x ----
        float acc2[20];
#pragma unroll
        for (int k = 0; k < 20; ++k) acc2[k] = 0.f;
#pragma unroll
        for (int c = 0; c < 8; ++c) {
            float4 w4 = *(const float4*)(wF2 + 4 * c);
#pragma unroll
            for (int k = 0; k < 20; ++k) {
                float4 t4 = *(const float4*)(SCR + k * 32 + 4 * c);
                acc2[k] = fmaf(w4.x, t4.x, acc2[k]);
                acc2[k] = fmaf(w4.y, t4.y, acc2[k]);
                acc2[k] = fmaf(w4.z, t4.z, acc2[k]);
                acc2[k] = fmaf(w4.w, t4.w, acc2[k]);
            }
        }
#pragma unroll
        for (int k = 0; k < 20; ++k) {
            float a = 1.f / (1.f + expf(-acc2[k]));
            int kidx = IDX[k];
            float gth = bxb[(size_t)kidx * 64 + l];   // coalesced 256 B row
            float v = RIF[k * 64 + l] * a * gth;
            v = v * gacth + bacth;
            v = fmaxf(v, 0.f) - xc;
            RIF[k * 64 + l] = v;
        }

        // ---- edge conv + bn + leaky + max over k ----
#pragma unroll
        for (int k = 0; k < 20; ++k) acc2[k] = base;
#pragma unroll
        for (int c = 0; c < 16; ++c) {
            float4 w4 = *(const float4*)(wEd + 4 * c);
#pragma unroll
            for (int k = 0; k < 20; ++k) {
                float4 r4 = *(const float4*)(RIF + k * 64 + 4 * c);
                acc2[k] = fmaf(w4.x, r4.x, acc2[k]);
                acc2[k] = fmaf(w4.y, r4.y, acc2[k]);
                acc2[k] = fmaf(w4.z, r4.z, acc2[k]);
                acc2[k] = fmaf(w4.w, r4.w, acc2[k]);
            }
        }
        float mx = -INFINITY;
#pragma unroll
        for (int k = 0; k < 20; ++k) {
            float v = acc2[k] * gedgh + beedgh;
            v = (v >= 0.f) ? v : NEG_SLOPE * v;
            mx = fmaxf(mx, v);
        }
        out[((size_t)b * OUT_ + l) * N_ + n] = mx;
    }
}

// ---------------------------------------------------------------------------
extern "C" void kernel_launch(void* const* d_in, const int* in_sizes, int n_in,
                              void* d_out, int out_size, void* d_ws, size_t ws_size,
                              hipStream_t stream) {
    (void)in_sizes; (void)n_in; (void)out_size; (void)ws_size;
    const float* pos     = (const float*)d_in[0];
    const float* x       = (const float*)d_in[1];
    const float* glf     = (const float*)d_in[2];
    const float* appf    = (const float*)d_in[3];
    const float* basis_W = (const float*)d_in[4];
    const float* dk_W1   = (const float*)d_in[5];
    const float* dk_b1   = (const float*)d_in[6];
    const float* dk_g1   = (const float*)d_in[7];
    const float* dk_be1  = (const float*)d_in[8];
    const float* dk_W2   = (const float*)d_in[9];
    const float* dk_b2   = (const float*)d_in[10];
    const float* act_g   = (const float*)d_in[11];
    const float* act_b   = (const float*)d_in[12];
    const float* ff_W1   = (const float*)d_in[13];
    const float* ff_g1   = (const float*)d_in[14];
    const float* ff_be1  = (const float*)d_in[15];
    const float* ff_W2   = (const float*)d_in[16];
    const float* edge_W  = (const float*)d_in[17];
    const float* edge_g  = (const float*)d_in[18];
    const float* edge_be = (const float*)d_in[19];
    float* out = (float*)d_out;

    int*   idx_ws = (int*)d_ws;
    float* bxT    = (float*)((char*)d_ws + (size_t)B_ * N_ * K_ * sizeof(int));

    hipLaunchKernelGGL(knn_kernel, dim3(B_ * N_ / 4), dim3(256), 0, stream,
                       pos, idx_ws);
    hipLaunchKernelGGL(bx_kernel_t, dim3(N_ / 32, B_), dim3(256), 0, stream,
                       x, basis_W, bxT);
    hipLaunchKernelGGL(fused_kernel, dim3(B_ * (N_ / NBLK)), dim3(256), 0, stream,
                       x, glf, appf, dk_W1, dk_b1, dk_g1, dk_be1, dk_W2, dk_b2,
                       act_g, act_b, ff_W1, ff_g1, ff_be1, ff_W2,
                       edge_W, edge_g, edge_be, bxT, idx_ws, out);
}